// Round 5
// baseline (298.089 us; speedup 1.0000x reference)
//
#include <hip/hip_runtime.h>
#include <hip/hip_bf16.h>

using bf16 = __hip_bfloat16;
typedef __bf16 bf16x8 __attribute__((ext_vector_type(8)));
typedef float f32x4 __attribute__((ext_vector_type(4)));

#define SH  264   // hs row stride (16B-aligned: 528 B)
#define SN2 24    // nt2 row stride (48 B): j 0..16 valid, 17..23 zero
#define SMS 40    // ms row stride (80 B)
// LDS pool (bf16 elems), 23200 total = 46400 B -> 3 blocks/CU:
//   nt2 @ 0     : 512*24 + 32 zero tail = 12320   (nodes, transposed (t*32+f) x j)
//   hs  @ 12320 : 16*264 = 4224                   (GEMM1 out; dead after GEMM2)
//   ms  @ 12320 : 272*40 = 10880                  (mix out / Wg A / final result)

__device__ __forceinline__ float bf2f(bf16 v) { return __bfloat162float(v); }

__device__ __forceinline__ float gelu_f(float x) {
    // 0.5x(1+tanh(0.79788(x+0.044715x^3))); tanh via 1-2/(1+exp(2u)) — sign-free
    float u = 0.7978845608f * x * (1.0f + 0.044715f * x * x);
    float e = __builtin_amdgcn_exp2f(2.88539008f * u);   // exp(2u) via v_exp_f32
    float t = 1.0f - 2.0f * __builtin_amdgcn_rcpf(1.0f + e);
    float h = 0.5f * x;
    return fmaf(h, t, h);
}

__device__ __forceinline__ bf16x8 ld8(const bf16* p) {
    return *reinterpret_cast<const bf16x8*>(p);
}
__device__ __forceinline__ f32x4 mfma16(bf16x8 a, bf16x8 b, f32x4 c) {
    return __builtin_amdgcn_mfma_f32_16x16x32_bf16(a, b, c, 0, 0, 0);
}

// ---------------- prep: transpose weights -> bf16 (coalesced 4-packs); bf16 softmax adjacency ----------------
__global__ void prep_kernel(const float* __restrict__ W1, const float* __restrict__ W2,
                            const float* __restrict__ Wg1, const float* __restrict__ Wg2,
                            const float* __restrict__ adj1, const float* __restrict__ adj2,
                            bf16* __restrict__ w1t, bf16* __restrict__ w2t,
                            bf16* __restrict__ wg1t, bf16* __restrict__ wg2t,
                            bf16* __restrict__ Ab) {
    int idx = blockIdx.x * 256 + threadIdx.x;
    if (idx < 8192) {                                  // w1t[n=c][k]: 256 x (32 packs of 4)
        int c = idx >> 5, rb = (idx & 31) * 4;
        bf16 tmp[4];
#pragma unroll
        for (int jj = 0; jj < 4; ++jj) tmp[jj] = __float2bfloat16(W1[(rb + jj) * 256 + c]);
        *reinterpret_cast<ushort4*>(w1t + c * 128 + rb) = *reinterpret_cast<const ushort4*>(tmp);
    } else if (idx < 43008) {                          // w2t[n=c][k]: 544 x (64 packs of 4)
        int j = idx - 8192;
        int c = j >> 6, rb = (j & 63) * 4;
        bf16 tmp[4];
#pragma unroll
        for (int jj = 0; jj < 4; ++jj) tmp[jj] = __float2bfloat16(W2[(rb + jj) * 544 + c]);
        *reinterpret_cast<ushort4*>(w2t + c * 256 + rb) = *reinterpret_cast<const ushort4*>(tmp);
    } else if (idx < 44032) {
        int j = idx - 43008;
        wg1t[(j & 31) * 32 + (j >> 5)] = __float2bfloat16(Wg1[j]);
    } else if (idx < 45056) {
        int j = idx - 44032;
        wg2t[(j & 31) * 32 + (j >> 5)] = __float2bfloat16(Wg2[j]);
    }
    if (blockIdx.x == 0 && threadIdx.x < 64) {
        int t = threadIdx.x;
        int g = t >> 5, row = t & 31;
        const float* adj = g ? adj2 : adj1;
        bf16* abp = Ab + g * 1024 + row * 32;          // Ab[g][i=row][j] zero-padded 32x32
        if (row < 17) {
            float v[17], mx = -1e30f;
            for (int jj = 0; jj < 17; ++jj) { v[jj] = adj[row * 17 + jj]; mx = fmaxf(mx, v[jj]); }
            float s = 0.0f;
            for (int jj = 0; jj < 17; ++jj) { v[jj] = __expf(v[jj] - mx); s += v[jj]; }
            float inv = 1.0f / s;
            for (int jj = 0; jj < 17; ++jj) abp[jj] = __float2bfloat16(v[jj] * inv);
            for (int jj = 17; jj < 32; ++jj) abp[jj] = __float2bfloat16(0.0f);
        } else {
            for (int jj = 0; jj < 32; ++jj) abp[jj] = __float2bfloat16(0.0f);
        }
    }
}

// ---------------- main fused kernel: 16 tokens/block ----------------
__global__ __launch_bounds__(256, 3)
void gat_main(const float* __restrict__ x,
              const float* __restrict__ b1, const float* __restrict__ b2,
              const float* __restrict__ bg1, const float* __restrict__ bg2,
              const bf16* __restrict__ w1t, const bf16* __restrict__ w2t,
              const bf16* __restrict__ wg1t, const bf16* __restrict__ wg2t,
              const bf16* __restrict__ Ab, const float* __restrict__ Wc,
              const float* __restrict__ bc, float* __restrict__ out) {
    __shared__ alignas(16) bf16 lds[23200];
    bf16* nt2 = lds;            // [512][24] + 32 tail
    bf16* hs  = lds + 12320;    // [16][264]
    bf16* ms  = lds + 12320;    // [272][40] (reuses hs region after GEMM2)

    const int tid  = threadIdx.x;
    const int w    = tid >> 6;
    const int lane = tid & 63;
    const int l    = lane & 15;
    const int q    = lane >> 4;
    const int t0   = blockIdx.x * 16;
    const f32x4 zero = {0.f, 0.f, 0.f, 0.f};

    // zero nt2 (incl. padded j-columns and tail) — pads must be finite for the mixing MFMA
    for (int c = tid * 8; c < 12320; c += 2048)
        *reinterpret_cast<int4*>(nt2 + c) = int4{0, 0, 0, 0};

    // ---- GEMM1: h = gelu(x @ W1 + b1), M=16; A direct from global fp32 ----
    bf16x8 a1[4];
    {
        const float* xp = x + (size_t)(t0 + l) * 128 + q * 8;
#pragma unroll
        for (int kf = 0; kf < 4; ++kf) {
            float4 v0 = *reinterpret_cast<const float4*>(xp + kf * 32);
            float4 v1 = *reinterpret_cast<const float4*>(xp + kf * 32 + 4);
            union { bf16 h[8]; bf16x8 v; } u;
            u.h[0] = __float2bfloat16(v0.x); u.h[1] = __float2bfloat16(v0.y);
            u.h[2] = __float2bfloat16(v0.z); u.h[3] = __float2bfloat16(v0.w);
            u.h[4] = __float2bfloat16(v1.x); u.h[5] = __float2bfloat16(v1.y);
            u.h[6] = __float2bfloat16(v1.z); u.h[7] = __float2bfloat16(v1.w);
            a1[kf] = u.v;
        }
    }
#pragma unroll
    for (int j = 0; j < 4; ++j) {
        int n = (w * 4 + j) * 16 + l;
        const bf16* wp = w1t + n * 128 + q * 8;
        f32x4 acc = zero;
#pragma unroll
        for (int kf = 0; kf < 4; ++kf)
            acc = mfma16(a1[kf], ld8(wp + kf * 32), acc);
        float bias = b1[n];
#pragma unroll
        for (int r = 0; r < 4; ++r)
            hs[(q * 4 + r) * SH + n] = __float2bfloat16(gelu_f(acc[r] + bias));
    }
    __syncthreads();

    // ---- GEMM2: nodes = h @ W2 + b2, M=16, N=544 -> write transposed nt2[(t*32+f)][i] ----
    bf16x8 a2[8];
#pragma unroll
    for (int kf = 0; kf < 8; ++kf)
        a2[kf] = ld8(hs + l * SH + kf * 32 + q * 8);
    for (int nt = w; nt < 34; nt += 4) {
        int n = nt * 16 + l;
        const bf16* wp = w2t + n * 256 + q * 8;
        f32x4 acc = zero;
#pragma unroll
        for (int kf = 0; kf < 8; ++kf)
            acc = mfma16(a2[kf], ld8(wp + kf * 32), acc);
        float bias = b2[n];
        int i = n >> 5, f = n & 31;
#pragma unroll
        for (int r = 0; r < 4; ++r)
            nt2[((q * 4 + r) * 32 + f) * SN2 + i] = __float2bfloat16(acc[r] + bias);
    }
    __syncthreads();

    // ---- two GAT layers ----
#pragma unroll
    for (int g = 0; g < 2; ++g) {
        const bf16* Abg = Ab + g * 1024;
        const bf16* wgt = g ? wg2t : wg1t;
        const float* bg = g ? bg2 : bg1;

        // mixing via MFMA: mixedT[(t*32+f)][i] = sum_j nt2[(t*32+f)][j] * A[i][j]
        bf16x8 bA0 = ld8(Abg + l * 32 + q * 8);          // B[k=j][col=i=l]      = A[l][j]
        bf16x8 bA1 = ld8(Abg + (16 + l) * 32 + q * 8);   // cols 16..31 (only i=16 real)
        for (int mt2 = w; mt2 < 32; mt2 += 4) {
            bf16x8 af = ld8(nt2 + (mt2 * 16 + l) * SN2 + q * 8);
            f32x4 c0 = mfma16(af, bA0, zero);
            f32x4 c1 = mfma16(af, bA1, zero);
            int t = mt2 >> 1, fb = (mt2 & 1) * 16 + q * 4;
            union { bf16 h[4]; ushort4 v4; } p0;
#pragma unroll
            for (int r = 0; r < 4; ++r) p0.h[r] = __float2bfloat16(c0[r]);
            *reinterpret_cast<ushort4*>(ms + (t * 17 + l) * SMS + fb) = p0.v4;
            if (l == 0) {
                union { bf16 h[4]; ushort4 v4; } p1;
#pragma unroll
                for (int r = 0; r < 4; ++r) p1.h[r] = __float2bfloat16(c1[r]);
                *reinterpret_cast<ushort4*>(ms + (t * 17 + 16) * SMS + fb) = p1.v4;
            }
        }
        __syncthreads();

        // Wg linear (K=32) + gelu + residual. M rows = (t*17+i), 17 tiles.
        bf16x8 wf0 = ld8(wgt + l * 32 + q * 8);
        bf16x8 wf1 = ld8(wgt + (16 + l) * 32 + q * 8);
        float bg0 = bg[l], bg1v = bg[16 + l];
        for (int mt = w; mt < 17; mt += 4) {
            bf16x8 af = ld8(ms + (mt * 16 + l) * SMS + q * 8);
            f32x4 c0 = mfma16(af, wf0, zero);
            f32x4 c1 = mfma16(af, wf1, zero);
#pragma unroll
            for (int r = 0; r < 4; ++r) {
                int rloc = mt * 16 + q * 4 + r;          // 0..271
                int t = rloc / 17;                       // magic-mul
                int i = rloc - t * 17;
                int base = (t * 32) * SN2 + i;
                float res0 = bf2f(nt2[base + l * SN2]);
                float res1 = bf2f(nt2[base + (16 + l) * SN2]);
                float v0 = gelu_f(c0[r] + bg0) + res0;
                float v1 = gelu_f(c1[r] + bg1v) + res1;
                if (g == 0) {                            // feed layer-2 mixing (nt2 layout)
                    nt2[base + l * SN2] = __float2bfloat16(v0);
                    nt2[base + (16 + l) * SN2] = __float2bfloat16(v1);
                } else {                                 // final nodes -> ms rows (coord-friendly)
                    ms[rloc * SMS + l] = __float2bfloat16(v0);
                    ms[rloc * SMS + 16 + l] = __float2bfloat16(v1);
                }
            }
        }
        __syncthreads();
    }

    // ---- coord projection: out[row] = ms_row @ Wc + bc (row = t*17+i, globally linear) ----
    for (int r = tid; r < 272; r += 256) {
        const bf16* mp = ms + r * SMS;
        float o0 = bc[0], o1 = bc[1];
#pragma unroll
        for (int k = 0; k < 32; ++k) {
            float a = bf2f(mp[k]);
            o0 = fmaf(a, Wc[k * 2 + 0], o0);
            o1 = fmaf(a, Wc[k * 2 + 1], o1);
        }
        float2 pr = { o0, o1 };
        *reinterpret_cast<float2*>(out + (size_t)(blockIdx.x * 272 + r) * 2) = pr;
    }
}

extern "C" void kernel_launch(void* const* d_in, const int* in_sizes, int n_in,
                              void* d_out, int out_size, void* d_ws, size_t ws_size,
                              hipStream_t stream) {
    const float* x    = (const float*)d_in[0];
    const float* W1   = (const float*)d_in[1];
    const float* b1   = (const float*)d_in[2];
    const float* W2   = (const float*)d_in[3];
    const float* b2   = (const float*)d_in[4];
    const float* adj1 = (const float*)d_in[5];
    const float* Wg1  = (const float*)d_in[6];
    const float* bg1  = (const float*)d_in[7];
    const float* adj2 = (const float*)d_in[8];
    const float* Wg2  = (const float*)d_in[9];
    const float* bg2  = (const float*)d_in[10];
    const float* Wc   = (const float*)d_in[11];
    const float* bc   = (const float*)d_in[12];

    char* ws = (char*)d_ws;
    bf16* w1t  = (bf16*)(ws + 0);        // 65536 B
    bf16* w2t  = (bf16*)(ws + 65536);    // 278528 B
    bf16* wg1t = (bf16*)(ws + 344064);   // 2048 B
    bf16* wg2t = (bf16*)(ws + 346112);   // 2048 B
    bf16* Ab   = (bf16*)(ws + 348160);   // 4096 B  (2 x 32 x 32 padded softmax adjacency)

    prep_kernel<<<176, 256, 0, stream>>>(W1, W2, Wg1, Wg2, adj1, adj2,
                                         w1t, w2t, wg1t, wg2t, Ab);

    gat_main<<<4096, 256, 0, stream>>>(x, b1, b2, bg1, bg2,
                                       w1t, w2t, wg1t, wg2t,
                                       Ab, Wc, bc, (float*)d_out);
}

// Round 8
// 284.177 us; speedup vs baseline: 1.0490x; 1.0490x over previous
//
#include <hip/hip_runtime.h>
#include <hip/hip_bf16.h>

using bf16 = __hip_bfloat16;
typedef __bf16 bf16x8 __attribute__((ext_vector_type(8)));
typedef float f32x4 __attribute__((ext_vector_type(4)));

#define SH  264   // hs row stride (528 B)
#define SN2 24    // nt2 row stride (48 B): j 0..16 valid, 17..23 pad (finite)
#define SMS 40    // ms row stride (80 B)
// LDS pool (bf16 elems), 23200 total = 46400 B -> 3 blocks/CU:
//   nt2 @ 0     : 512*24 + 32 tail = 12320
//   hs  @ 12320 : 16*264 = 4224   (dead after GEMM2)
//   ms  @ 12320 : 272*40 = 10880  (mix out / Wg A / final result)

__device__ __forceinline__ float bf2f(bf16 v) { return __bfloat162float(v); }

__device__ __forceinline__ float gelu_f(float x) {
    float u = 0.7978845608f * x * (1.0f + 0.044715f * x * x);
    float e = __builtin_amdgcn_exp2f(2.88539008f * u);   // exp(2u)
    float t = 1.0f - 2.0f * __builtin_amdgcn_rcpf(1.0f + e);
    float h = 0.5f * x;
    return fmaf(h, t, h);
}

__device__ __forceinline__ bf16x8 ld8(const bf16* p) {
    return *reinterpret_cast<const bf16x8*>(p);
}
__device__ __forceinline__ f32x4 mfma16(bf16x8 a, bf16x8 b, f32x4 c) {
    return __builtin_amdgcn_mfma_f32_16x16x32_bf16(a, b, c, 0, 0, 0);
}

// ---------------- prep: coalesced 32x32 tiled transpose fp32->bf16 ----------------
// blocks 0..31: W1 (4 k-tiles x 8 n-tiles) -> w1t[256][128]
// blocks 32..167: W2 (8 k-tiles x 17 n-tiles) -> w2t[544][256]
// block 168: wg1t/wg2t transpose, Ab softmax
__global__ void prep_kernel(const float* __restrict__ W1, const float* __restrict__ W2,
                            const float* __restrict__ Wg1, const float* __restrict__ Wg2,
                            const float* __restrict__ adj1, const float* __restrict__ adj2,
                            bf16* __restrict__ w1t, bf16* __restrict__ w2t,
                            bf16* __restrict__ wg1t, bf16* __restrict__ wg2t,
                            bf16* __restrict__ Ab) {
    __shared__ float tile[32][33];
    const int b = blockIdx.x, tid = threadIdx.x;
    if (b < 168) {
        const float* src; bf16* dst; int tr, tc, srcld, dstld;
        if (b < 32) { src = W1; dst = w1t; tr = b >> 3; tc = b & 7; srcld = 256; dstld = 128; }
        else        { src = W2; dst = w2t; tr = (b - 32) / 17; tc = (b - 32) % 17; srcld = 544; dstld = 256; }
        int ri = tid >> 3, ci4 = (tid & 7) * 4;
        float4 v = *reinterpret_cast<const float4*>(src + (size_t)(tr * 32 + ri) * srcld + tc * 32 + ci4);
        tile[ri][ci4 + 0] = v.x; tile[ri][ci4 + 1] = v.y;
        tile[ri][ci4 + 2] = v.z; tile[ri][ci4 + 3] = v.w;
        __syncthreads();
        int nr = tid >> 3, kb = (tid & 7) * 4;
        bf16 tmp[4];
#pragma unroll
        for (int jj = 0; jj < 4; ++jj) tmp[jj] = __float2bfloat16(tile[kb + jj][nr]);
        *reinterpret_cast<ushort4*>(dst + (size_t)(tc * 32 + nr) * dstld + tr * 32 + kb) =
            *reinterpret_cast<const ushort4*>(tmp);
    } else {
        // small weights transpose
        for (int idx = tid; idx < 2048; idx += 256) {
            int g = idx >> 10, j = idx & 1023;
            const float* s = g ? Wg2 : Wg1;
            bf16* d = g ? wg2t : wg1t;
            d[(j & 31) * 32 + (j >> 5)] = __float2bfloat16(s[j]);
        }
        // softmax adjacency -> bf16, zero-padded 32x32 per layer
        if (tid < 64) {
            int g = tid >> 5, row = tid & 31;
            const float* adj = g ? adj2 : adj1;
            bf16* abp = Ab + g * 1024 + row * 32;
            if (row < 17) {
                float v[17], mx = -1e30f;
                for (int jj = 0; jj < 17; ++jj) { v[jj] = adj[row * 17 + jj]; mx = fmaxf(mx, v[jj]); }
                float s = 0.0f;
                for (int jj = 0; jj < 17; ++jj) { v[jj] = __expf(v[jj] - mx); s += v[jj]; }
                float inv = 1.0f / s;
                for (int jj = 0; jj < 17; ++jj) abp[jj] = __float2bfloat16(v[jj] * inv);
                for (int jj = 17; jj < 32; ++jj) abp[jj] = __float2bfloat16(0.0f);
            } else {
                for (int jj = 0; jj < 32; ++jj) abp[jj] = __float2bfloat16(0.0f);
            }
        }
    }
}

// ---------------- main fused kernel: 16 tokens/block (R5 numerics) ----------------
__global__ __launch_bounds__(256, 3)
void gat_main(const float* __restrict__ x,
              const float* __restrict__ b1, const float* __restrict__ b2,
              const float* __restrict__ bg1, const float* __restrict__ bg2,
              const bf16* __restrict__ w1t, const bf16* __restrict__ w2t,
              const bf16* __restrict__ wg1t, const bf16* __restrict__ wg2t,
              const bf16* __restrict__ Ab, const float* __restrict__ Wc,
              const float* __restrict__ bc, float* __restrict__ out) {
    __shared__ alignas(16) bf16 lds[23200];
    bf16* nt2 = lds;            // [512][24] + 32 tail
    bf16* hs  = lds + 12320;    // [16][264]
    bf16* ms  = lds + 12320;    // [272][40] (aliases hs after GEMM2)

    const int tid  = threadIdx.x;
    const int w    = tid >> 6;
    const int lane = tid & 63;
    const int l    = lane & 15;
    const int q    = lane >> 4;
    const int t0   = blockIdx.x * 16;
    const f32x4 zero = {0.f, 0.f, 0.f, 0.f};

    // zero nt2 (pads must be FINITE: garbage can be NaN-patterned, NaN*0=NaN in MFMA)
    for (int c = tid * 8; c < 12320; c += 2048)
        *reinterpret_cast<int4*>(nt2 + c) = int4{0, 0, 0, 0};

    // ---- GEMM1: h = gelu(x @ W1 + b1), M=16; x direct from global ----
    {
        bf16x8 a1[4];
        const float* xp = x + (size_t)(t0 + l) * 128 + q * 8;
#pragma unroll
        for (int kf = 0; kf < 4; ++kf) {
            float4 v0 = *reinterpret_cast<const float4*>(xp + kf * 32);
            float4 v1 = *reinterpret_cast<const float4*>(xp + kf * 32 + 4);
            union { bf16 h[8]; bf16x8 v; } u;
            u.h[0] = __float2bfloat16(v0.x); u.h[1] = __float2bfloat16(v0.y);
            u.h[2] = __float2bfloat16(v0.z); u.h[3] = __float2bfloat16(v0.w);
            u.h[4] = __float2bfloat16(v1.x); u.h[5] = __float2bfloat16(v1.y);
            u.h[6] = __float2bfloat16(v1.z); u.h[7] = __float2bfloat16(v1.w);
            a1[kf] = u.v;
        }
        // hoist ALL B-fragments (16 x 16B loads in flight together)
        bf16x8 bf1[4][4];
#pragma unroll
        for (int j = 0; j < 4; ++j) {
            const bf16* wp = w1t + (size_t)((w * 4 + j) * 16 + l) * 128 + q * 8;
#pragma unroll
            for (int kf = 0; kf < 4; ++kf) bf1[j][kf] = ld8(wp + kf * 32);
        }
#pragma unroll
        for (int j = 0; j < 4; ++j) {
            int n = (w * 4 + j) * 16 + l;
            f32x4 acc = zero;
#pragma unroll
            for (int kf = 0; kf < 4; ++kf)
                acc = mfma16(a1[kf], bf1[j][kf], acc);
            float bias = b1[n];
#pragma unroll
            for (int r = 0; r < 4; ++r)
                hs[(q * 4 + r) * SH + n] = __float2bfloat16(gelu_f(acc[r] + bias));
        }
    }
    __syncthreads();

    // ---- GEMM2: nodes = h @ W2 + b2 -> nt2[(t*32+f)][i]; double-buffered B, clamped prefetch ----
    {
        bf16x8 a2[8];
#pragma unroll
        for (int kf = 0; kf < 8; ++kf)
            a2[kf] = ld8(hs + l * SH + kf * 32 + q * 8);
        bf16x8 bcur[8], bnxt[8];
        int nt = w;
        const bf16* wp0 = w2t + (size_t)(nt * 16 + l) * 256 + q * 8;
#pragma unroll
        for (int kf = 0; kf < 8; ++kf) bcur[kf] = ld8(wp0 + kf * 32);
#pragma unroll
        for (int it = 0; it < 9; ++it) {
            if (it < 8) {
                int ntn = (nt + 4 < 34) ? nt + 4 : w;        // clamp to a valid tile
                const bf16* wpn = w2t + (size_t)(ntn * 16 + l) * 256 + q * 8;
#pragma unroll
                for (int kf = 0; kf < 8; ++kf) bnxt[kf] = ld8(wpn + kf * 32);
            }
            if (nt < 34) {                                   // wave-uniform liveness
                f32x4 acc = zero;
#pragma unroll
                for (int kf = 0; kf < 8; ++kf)
                    acc = mfma16(a2[kf], bcur[kf], acc);
                int n = nt * 16 + l;
                float bias = b2[n];
                int i = n >> 5, f = n & 31;
#pragma unroll
                for (int r = 0; r < 4; ++r)
                    nt2[((q * 4 + r) * 32 + f) * SN2 + i] = __float2bfloat16(acc[r] + bias);
            }
#pragma unroll
            for (int kf = 0; kf < 8; ++kf) bcur[kf] = bnxt[kf];
            nt += 4;
        }
    }
    __syncthreads();

    // ---- two GAT layers (R5 numerics, incl. ms-based final storage) ----
#pragma unroll
    for (int g = 0; g < 2; ++g) {
        const bf16* Abg = Ab + g * 1024;
        const bf16* wgt = g ? wg2t : wg1t;
        const float* bg = g ? bg2 : bg1;

        // mixing via MFMA: mixedT[(t*32+f)][i] = sum_j nt2[(t*32+f)][j] * A[i][j]
        bf16x8 bA0 = ld8(Abg + l * 32 + q * 8);
        bf16x8 bA1 = ld8(Abg + (16 + l) * 32 + q * 8);
#pragma unroll
        for (int it = 0; it < 8; ++it) {
            int mt2 = it * 4 + w;
            bf16x8 af = ld8(nt2 + (mt2 * 16 + l) * SN2 + q * 8);
            f32x4 c0 = mfma16(af, bA0, zero);
            f32x4 c1 = mfma16(af, bA1, zero);
            int t = mt2 >> 1, fb = (mt2 & 1) * 16 + q * 4;
            union { bf16 h[4]; ushort4 v4; } p0;
#pragma unroll
            for (int r = 0; r < 4; ++r) p0.h[r] = __float2bfloat16(c0[r]);
            *reinterpret_cast<ushort4*>(ms + (t * 17 + l) * SMS + fb) = p0.v4;
            if (l == 0) {
                union { bf16 h[4]; ushort4 v4; } p1;
#pragma unroll
                for (int r = 0; r < 4; ++r) p1.h[r] = __float2bfloat16(c1[r]);
                *reinterpret_cast<ushort4*>(ms + (t * 17 + 16) * SMS + fb) = p1.v4;
            }
        }
        __syncthreads();

        // Wg linear (K=32) + gelu + residual; rows = t*17+i (272 = 17 tiles)
        bf16x8 wf0 = ld8(wgt + l * 32 + q * 8);
        bf16x8 wf1 = ld8(wgt + (16 + l) * 32 + q * 8);
        float bg0 = bg[l], bg1v = bg[16 + l];
#pragma unroll
        for (int it = 0; it < 5; ++it) {
            int mt = it * 4 + w;
            if (mt < 17) {
                bf16x8 af = ld8(ms + (mt * 16 + l) * SMS + q * 8);
                f32x4 c0 = mfma16(af, wf0, zero);
                f32x4 c1 = mfma16(af, wf1, zero);
#pragma unroll
                for (int r = 0; r < 4; ++r) {
                    int rloc = mt * 16 + q * 4 + r;          // 0..271
                    int t = rloc / 17;
                    int i = rloc - t * 17;
                    int base = (t * 32) * SN2 + i;
                    float res0 = bf2f(nt2[base + l * SN2]);
                    float res1 = bf2f(nt2[base + (16 + l) * SN2]);
                    float v0 = gelu_f(c0[r] + bg0) + res0;
                    float v1 = gelu_f(c1[r] + bg1v) + res1;
                    if (g == 0) {                            // feed layer-2 mixing
                        nt2[base + l * SN2] = __float2bfloat16(v0);
                        nt2[base + (16 + l) * SN2] = __float2bfloat16(v1);
                    } else {                                 // final nodes -> ms rows
                        ms[rloc * SMS + l] = __float2bfloat16(v0);
                        ms[rloc * SMS + 16 + l] = __float2bfloat16(v1);
                    }
                }
            }
        }
        __syncthreads();
    }

    // ---- coord projection: out[row] = ms_row @ Wc + bc (R5's exact path) ----
    for (int r = tid; r < 272; r += 256) {
        const bf16* mp = ms + r * SMS;
        float o0 = bc[0], o1 = bc[1];
#pragma unroll
        for (int k = 0; k < 32; ++k) {
            float a = bf2f(mp[k]);
            o0 = fmaf(a, Wc[k * 2 + 0], o0);
            o1 = fmaf(a, Wc[k * 2 + 1], o1);
        }
        float2 pr = { o0, o1 };
        *reinterpret_cast<float2*>(out + (size_t)(blockIdx.x * 272 + r) * 2) = pr;
    }
}

extern "C" void kernel_launch(void* const* d_in, const int* in_sizes, int n_in,
                              void* d_out, int out_size, void* d_ws, size_t ws_size,
                              hipStream_t stream) {
    const float* x    = (const float*)d_in[0];
    const float* W1   = (const float*)d_in[1];
    const float* b1   = (const float*)d_in[2];
    const float* W2   = (const float*)d_in[3];
    const float* b2   = (const float*)d_in[4];
    const float* adj1 = (const float*)d_in[5];
    const float* Wg1  = (const float*)d_in[6];
    const float* bg1  = (const float*)d_in[7];
    const float* adj2 = (const float*)d_in[8];
    const float* Wg2  = (const float*)d_in[9];
    const float* bg2  = (const float*)d_in[10];
    const float* Wc   = (const float*)d_in[11];
    const float* bc   = (const float*)d_in[12];

    // ws layout: exact footprint R5 validated in-bounds (<= 352256 B)
    char* ws = (char*)d_ws;
    bf16* w1t  = (bf16*)(ws + 0);        // 256x128 bf16 = 65536 B
    bf16* w2t  = (bf16*)(ws + 65536);    // 544x256 bf16 = 278528 B
    bf16* wg1t = (bf16*)(ws + 344064);   // 2048 B
    bf16* wg2t = (bf16*)(ws + 346112);   // 2048 B
    bf16* Ab   = (bf16*)(ws + 348160);   // 4096 B

    prep_kernel<<<169, 256, 0, stream>>>(W1, W2, Wg1, Wg2, adj1, adj2,
                                         w1t, w2t, wg1t, wg2t, Ab);

    gat_main<<<4096, 256, 0, stream>>>(x, b1, b2, bg1, bg2,
                                       w1t, w2t, wg1t, wg2t,
                                       Ab, Wc, bc, (float*)d_out);
}